// Round 1
// baseline (793.577 us; speedup 1.0000x reference)
//
#include <hip/hip_runtime.h>
#include <math.h>

constexpr int N_NODES = 100000;
constexpr int DIM     = 128;
constexpr int M_NNZ   = 3200000;
constexpr int E_EDGES = 200000;
constexpr int P_PAIRS = 500000;

__global__ void zero_kernel(float* __restrict__ p, int n) {
    int i = blockIdx.x * blockDim.x + threadIdx.x;
    if (i < n) p[i] = 0.f;
}

// h0[i] = x[i] + (sum_{j in N(i)} x[j]) / (deg(i) + 1e-6)
// One block (128 threads) per node; nnz range via binary search on sorted adj_row.
__global__ __launch_bounds__(128) void agg_kernel(
    const float* __restrict__ x, const int* __restrict__ adj_row,
    const int* __restrict__ adj_col, float* __restrict__ h0) {
    const int node = blockIdx.x;
    const int tid  = threadIdx.x;

    int lo = 0, hi = M_NNZ;
    while (lo < hi) { int mid = (lo + hi) >> 1; if (adj_row[mid] < node) lo = mid + 1; else hi = mid; }
    const int start = lo;
    hi = M_NNZ;
    while (lo < hi) { int mid = (lo + hi) >> 1; if (adj_row[mid] <= node) lo = mid + 1; else hi = mid; }
    const int end = lo;

    const float deg = (float)(end - start) + 1e-6f;

    __shared__ int cols[128];
    float sum = 0.f;
    for (int base = start; base < end; base += 128) {
        const int n = min(128, end - base);
        __syncthreads();
        if (tid < n) cols[tid] = adj_col[base + tid];
        __syncthreads();
        #pragma unroll 4
        for (int j = 0; j < n; ++j)
            sum += x[(size_t)cols[j] * DIM + tid];
    }
    const size_t off = (size_t)node * DIM + tid;
    h0[off] = x[off] + sum / deg;
}

// C = (relu?)(A @ W + b); A [nrows x 128], W [128 x 128] row-major, full K in one pass.
// Block: 32 rows x 128 cols, 256 threads, each computes 4 rows x 4 cols.
// A tile staged transposed in LDS ([k][r], padded); W streamed from global (L1/L2-resident).
template <bool RELU>
__global__ __launch_bounds__(256) void mlp_gemm(
    const float* __restrict__ A, const float* __restrict__ W,
    const float* __restrict__ bias, float* __restrict__ C) {
    __shared__ __align__(16) float As[128][36];  // [k][r], +4 pad keeps float4 alignment
    const int tid = threadIdx.x;
    const int tx  = tid & 31;   // col group: cols 4*tx .. 4*tx+3
    const int ty  = tid >> 5;   // row group: rows 4*ty .. 4*ty+3
    const int rowBase = blockIdx.x * 32;

    // Stage A tile (32 rows x 128 cols) transposed into LDS.
    const float4* A4 = (const float4*)(A + (size_t)rowBase * DIM);
    #pragma unroll
    for (int i = 0; i < 4; ++i) {
        const int f  = tid + 256 * i;   // 0..1023 float4s
        const int r  = f >> 5;
        const int c4 = f & 31;
        const float4 a = A4[f];
        As[4 * c4 + 0][r] = a.x;
        As[4 * c4 + 1][r] = a.y;
        As[4 * c4 + 2][r] = a.z;
        As[4 * c4 + 3][r] = a.w;
    }
    __syncthreads();

    const float4 bb = *(const float4*)(bias + 4 * tx);
    const float4* W4 = (const float4*)W;  // W4[k*32 + c4] = W[k][4c4..4c4+3]

    float acc[4][4] = {};
    #pragma unroll 8
    for (int k = 0; k < 128; ++k) {
        const float4 w = W4[k * 32 + tx];
        const float4 a = *(const float4*)&As[k][4 * ty];
        const float av[4] = {a.x, a.y, a.z, a.w};
        const float wv[4] = {w.x, w.y, w.z, w.w};
        #pragma unroll
        for (int i = 0; i < 4; ++i)
            #pragma unroll
            for (int j = 0; j < 4; ++j)
                acc[i][j] += av[i] * wv[j];
    }

    #pragma unroll
    for (int i = 0; i < 4; ++i) {
        const int r = rowBase + 4 * ty + i;
        float4 o;
        o.x = acc[i][0] + bb.x;
        o.y = acc[i][1] + bb.y;
        o.z = acc[i][2] + bb.z;
        o.w = acc[i][3] + bb.w;
        if (RELU) {
            o.x = fmaxf(o.x, 0.f);
            o.y = fmaxf(o.y, 0.f);
            o.z = fmaxf(o.z, 0.f);
            o.w = fmaxf(o.w, 0.f);
        }
        *(float4*)(C + (size_t)r * DIM + 4 * tx) = o;
    }
}

// norms[i] = ||h[i]||; one wave (64 lanes) per row, float2 per lane.
__global__ __launch_bounds__(256) void norm_kernel(
    const float* __restrict__ h, float* __restrict__ norms) {
    const int wave = threadIdx.x >> 6, lane = threadIdx.x & 63;
    const int row  = blockIdx.x * 4 + wave;
    const float2 v = *(const float2*)(h + (size_t)row * DIM + lane * 2);
    float s = v.x * v.x + v.y * v.y;
    #pragma unroll
    for (int off = 32; off; off >>= 1) s += __shfl_xor(s, off);
    if (lane == 0) norms[row] = sqrtf(s);
}

// One wave per common-neighbor pair: w = cos(hu,hc)*cos(hv,hc), atomicAdd into scores[e].
__global__ __launch_bounds__(256) void pair_kernel(
    const float* __restrict__ h, const float* __restrict__ norms,
    const int* __restrict__ edges, const int* __restrict__ cn_edge_idx,
    const int* __restrict__ cn_node, float* __restrict__ scores) {
    const int wave = threadIdx.x >> 6, lane = threadIdx.x & 63;
    const int p = blockIdx.x * 4 + wave;

    const int e = cn_edge_idx[p];
    const int u = edges[e];
    const int v = edges[E_EDGES + e];
    const int c = cn_node[p];

    const float2 hu = *(const float2*)(h + (size_t)u * DIM + lane * 2);
    const float2 hv = *(const float2*)(h + (size_t)v * DIM + lane * 2);
    const float2 hc = *(const float2*)(h + (size_t)c * DIM + lane * 2);

    float duc = hu.x * hc.x + hu.y * hc.y;
    float dvc = hv.x * hc.x + hv.y * hc.y;
    #pragma unroll
    for (int off = 32; off; off >>= 1) {
        duc += __shfl_xor(duc, off);
        dvc += __shfl_xor(dvc, off);
    }
    if (lane == 0) {
        const float nu = norms[u], nv = norms[v], nc = norms[c];
        const float c1 = duc / fmaxf(nu * nc, 1e-8f);
        const float c2 = dvc / fmaxf(nv * nc, 1e-8f);
        atomicAdd(&scores[e], c1 * c2);
    }
}

__global__ void sigmoid_kernel(const float* __restrict__ scores,
                               float* __restrict__ out, int n) {
    int i = blockIdx.x * blockDim.x + threadIdx.x;
    if (i < n) out[i] = 1.f / (1.f + expf(-scores[i]));
}

extern "C" void kernel_launch(void* const* d_in, const int* in_sizes, int n_in,
                              void* d_out, int out_size, void* d_ws, size_t ws_size,
                              hipStream_t stream) {
    const float* x        = (const float*)d_in[0];
    const int* adj_row    = (const int*)d_in[1];
    const int* adj_col    = (const int*)d_in[2];
    const int* edges      = (const int*)d_in[3];   // [2, E] row-major
    const int* cn_edge    = (const int*)d_in[4];
    const int* cn_node    = (const int*)d_in[5];
    // d_in[6] = cn_valid: all true by construction; ignored.
    const float* W1 = (const float*)d_in[7];
    const float* b1 = (const float*)d_in[8];
    const float* W2 = (const float*)d_in[9];
    const float* b2 = (const float*)d_in[10];
    const float* W3 = (const float*)d_in[11];
    const float* b3 = (const float*)d_in[12];
    float* out = (float*)d_out;

    float* bufA   = (float*)d_ws;                       // [N,128]
    float* bufB   = bufA + (size_t)N_NODES * DIM;       // [N,128]
    float* norms  = bufB + (size_t)N_NODES * DIM;       // [N]
    float* scores = norms + N_NODES;                    // [E]

    zero_kernel<<<(E_EDGES + 255) / 256, 256, 0, stream>>>(scores, E_EDGES);
    agg_kernel<<<N_NODES, 128, 0, stream>>>(x, adj_row, adj_col, bufA);
    mlp_gemm<true ><<<N_NODES / 32, 256, 0, stream>>>(bufA, W1, b1, bufB);
    mlp_gemm<true ><<<N_NODES / 32, 256, 0, stream>>>(bufB, W2, b2, bufA);
    mlp_gemm<false><<<N_NODES / 32, 256, 0, stream>>>(bufA, W3, b3, bufB);
    norm_kernel<<<N_NODES / 4, 256, 0, stream>>>(bufB, norms);
    pair_kernel<<<P_PAIRS / 4, 256, 0, stream>>>(bufB, norms, edges, cn_edge, cn_node, scores);
    sigmoid_kernel<<<(E_EDGES + 255) / 256, 256, 0, stream>>>(scores, out, E_EDGES);
}

// Round 2
// 506.096 us; speedup vs baseline: 1.5680x; 1.5680x over previous
//
#include <hip/hip_runtime.h>
#include <math.h>

constexpr int N_NODES = 100000;
constexpr int DIM     = 128;
constexpr int M_NNZ   = 3200000;
constexpr int E_EDGES = 200000;
constexpr int P_PAIRS = 500000;

typedef _Float16 half8  __attribute__((ext_vector_type(8)));
typedef _Float16 half4t __attribute__((ext_vector_type(4)));
typedef _Float16 half2t __attribute__((ext_vector_type(2)));
typedef float    f32x4  __attribute__((ext_vector_type(4)));

__global__ void zero_kernel(int* __restrict__ p, int n) {
    int i = blockIdx.x * blockDim.x + threadIdx.x;
    if (i < n) p[i] = 0;
}

// xh = (fp16)x, 4 elems/thread
__global__ void cast_x_kernel(const float* __restrict__ x, _Float16* __restrict__ xh, int n4) {
    int i = blockIdx.x * blockDim.x + threadIdx.x;
    if (i < n4) {
        float4 v = ((const float4*)x)[i];
        half4t o = { (_Float16)v.x, (_Float16)v.y, (_Float16)v.z, (_Float16)v.w };
        ((half4t*)xh)[i] = o;
    }
}

// Wt[m][n][k] = (fp16) W_m[k][n]  (transposed so B-fragments are contiguous 16B)
__global__ void cast_wt_kernel(const float* __restrict__ W1, const float* __restrict__ W2,
                               const float* __restrict__ W3, _Float16* __restrict__ Wt) {
    int tid = blockIdx.x * blockDim.x + threadIdx.x;  // 3*128*128
    int m = tid >> 14, n = (tid >> 7) & 127, k = tid & 127;
    const float* W = (m == 0) ? W1 : (m == 1) ? W2 : W3;
    Wt[tid] = (_Float16)W[k * DIM + n];
}

// Segment boundaries of a sorted index array: rs[v]=first idx, re[v]=last idx+1.
// rs/re must be zeroed first (absent segments -> start=end=0).
__global__ void bounds_kernel(const int* __restrict__ arr, int len,
                              int* __restrict__ rs, int* __restrict__ re) {
    int p = blockIdx.x * blockDim.x + threadIdx.x;
    if (p >= len) return;
    int v = arr[p];
    if (p == 0 || arr[p - 1] != v) rs[v] = p;
    if (p == len - 1 || arr[p + 1] != v) re[v] = p + 1;
}

// h0[i] = fp16( x[i] + (sum_{j in N(i)} xh[j]) / (deg+1e-6) ); one 128-thread block/node.
__global__ __launch_bounds__(128) void agg_kernel(
    const float* __restrict__ x, const _Float16* __restrict__ xh,
    const int* __restrict__ rs, const int* __restrict__ re,
    const int* __restrict__ adj_col, _Float16* __restrict__ h0) {
    const int node = blockIdx.x, tid = threadIdx.x;
    const int start = rs[node], end = re[node];
    const float deg = (float)(end - start) + 1e-6f;

    __shared__ int cols[128];
    float sum = 0.f;
    for (int base = start; base < end; base += 128) {
        const int n = min(128, end - base);
        __syncthreads();
        if (tid < n) cols[tid] = adj_col[base + tid];
        __syncthreads();
        #pragma unroll 4
        for (int j = 0; j < n; ++j)
            sum += (float)xh[(size_t)cols[j] * DIM + tid];
    }
    const size_t off = (size_t)node * DIM + tid;
    h0[off] = (_Float16)(x[off] + sum / deg);
}

// C = (relu?)(A @ W + b), A [N x 128] fp16, Wt [128 x 128] fp16 pre-transposed.
// 256 thr = 4 waves; wave w computes rows rBase+w*16..+15, all 128 cols via
// 8 col-tiles x 4 K-steps of mfma_f32_16x16x32_f16. No LDS (Wt is L1-resident).
template <bool RELU>
__global__ __launch_bounds__(256) void gemm_f16(
    const _Float16* __restrict__ A, const _Float16* __restrict__ Wt,
    const float* __restrict__ bias, _Float16* __restrict__ C) {
    const int lane = threadIdx.x & 63;
    const int wave = threadIdx.x >> 6;
    const int rBase = blockIdx.x * 64 + wave * 16;
    const int q = lane >> 4;      // quad: k-group for A/B, row-group for C/D
    const int l16 = lane & 15;

    int r = rBase + l16;
    if (r > N_NODES - 1) r = N_NODES - 1;  // clamp tail loads
    const _Float16* Ap = A + (size_t)r * DIM + q * 8;
    half8 aF[4];
    #pragma unroll
    for (int t = 0; t < 4; ++t) aF[t] = *(const half8*)(Ap + t * 32);

    #pragma unroll
    for (int c = 0; c < 8; ++c) {
        const int col = c * 16 + l16;
        f32x4 acc = {0.f, 0.f, 0.f, 0.f};
        const _Float16* Wp = Wt + (size_t)col * DIM + q * 8;
        #pragma unroll
        for (int t = 0; t < 4; ++t) {
            half8 bF = *(const half8*)(Wp + t * 32);
            acc = __builtin_amdgcn_mfma_f32_16x16x32_f16(aF[t], bF, acc, 0, 0, 0);
        }
        const float bb = bias[col];
        #pragma unroll
        for (int reg = 0; reg < 4; ++reg) {
            const int row = rBase + q * 4 + reg;   // C/D: col=lane&15, row=quad*4+reg
            if (row < N_NODES) {
                float v = acc[reg] + bb;
                if (RELU) v = fmaxf(v, 0.f);
                C[(size_t)row * DIM + col] = (_Float16)v;
            }
        }
    }
}

// norms[i] = ||h[i]||; one wave per row, half2/lane.
__global__ __launch_bounds__(256) void norm_kernel(
    const _Float16* __restrict__ h, float* __restrict__ norms) {
    const int wave = threadIdx.x >> 6, lane = threadIdx.x & 63;
    const int row = blockIdx.x * 4 + wave;
    half2t v = *(const half2t*)(h + (size_t)row * DIM + lane * 2);
    const float a = (float)v.x, b = (float)v.y;
    float s = a * a + b * b;
    #pragma unroll
    for (int off = 32; off; off >>= 1) s += __shfl_xor(s, off);
    if (lane == 0) norms[row] = sqrtf(s);
}

// One wave per QUERY EDGE: reuse hu/hv across its pairs, no atomics, fused sigmoid.
__global__ __launch_bounds__(256) void edge_kernel(
    const _Float16* __restrict__ h, const float* __restrict__ norms,
    const int* __restrict__ edges, const int* __restrict__ es,
    const int* __restrict__ ee, const int* __restrict__ cn_node,
    float* __restrict__ out) {
    const int wave = threadIdx.x >> 6, lane = threadIdx.x & 63;
    const int e = blockIdx.x * 4 + wave;

    const int start = es[e], end = ee[e];
    float sum = 0.f;
    if (end > start) {
        const int u = edges[e];
        const int v = edges[E_EDGES + e];
        half2t hu2 = *(const half2t*)(h + (size_t)u * DIM + lane * 2);
        half2t hv2 = *(const half2t*)(h + (size_t)v * DIM + lane * 2);
        const float hux = (float)hu2.x, huy = (float)hu2.y;
        const float hvx = (float)hv2.x, hvy = (float)hv2.y;
        const float nu = norms[u], nv = norms[v];
        for (int p = start; p < end; ++p) {
            const int c = cn_node[p];
            half2t hc2 = *(const half2t*)(h + (size_t)c * DIM + lane * 2);
            const float hcx = (float)hc2.x, hcy = (float)hc2.y;
            float duc = hux * hcx + huy * hcy;
            float dvc = hvx * hcx + hvy * hcy;
            #pragma unroll
            for (int off = 32; off; off >>= 1) {
                duc += __shfl_xor(duc, off);
                dvc += __shfl_xor(dvc, off);
            }
            const float nc = norms[c];
            sum += (duc / fmaxf(nu * nc, 1e-8f)) * (dvc / fmaxf(nv * nc, 1e-8f));
        }
    }
    if (lane == 0) out[e] = 1.f / (1.f + expf(-sum));
}

extern "C" void kernel_launch(void* const* d_in, const int* in_sizes, int n_in,
                              void* d_out, int out_size, void* d_ws, size_t ws_size,
                              hipStream_t stream) {
    const float* x     = (const float*)d_in[0];
    const int* adj_row = (const int*)d_in[1];
    const int* adj_col = (const int*)d_in[2];
    const int* edges   = (const int*)d_in[3];
    const int* cn_edge = (const int*)d_in[4];
    const int* cn_node = (const int*)d_in[5];
    // d_in[6] = cn_valid: all true; ignored.
    const float* W1 = (const float*)d_in[7];
    const float* b1 = (const float*)d_in[8];
    const float* W2 = (const float*)d_in[9];
    const float* b2 = (const float*)d_in[10];
    const float* W3 = (const float*)d_in[11];
    const float* b3 = (const float*)d_in[12];
    float* out = (float*)d_out;

    char* base = (char*)d_ws;
    _Float16* xh = (_Float16*)base;                         // 25.6 MB
    _Float16* hA = (_Float16*)(base + 25600000);            // 25.6 MB
    _Float16* hB = (_Float16*)(base + 51200000);            // 25.6 MB
    _Float16* Wt = (_Float16*)(base + 76800000);            // 196608 B
    float*    norms = (float*)(base + 76996608);            // 400000 B
    int*      rs = (int*)(base + 77396608);                 // 400000 B
    int*      re = (int*)(base + 77796608);                 // 400000 B
    int*      es = (int*)(base + 78196608);                 // 800000 B
    int*      ee = (int*)(base + 78996608);                 // 800000 B  (end: 79.8 MB)

    // rs|re|es|ee are contiguous: zero all 2N+2E ints in one call
    zero_kernel<<<(2 * N_NODES + 2 * E_EDGES + 255) / 256, 256, 0, stream>>>(rs, 2 * N_NODES + 2 * E_EDGES);
    cast_x_kernel<<<(N_NODES * DIM / 4 + 255) / 256, 256, 0, stream>>>(x, xh, N_NODES * DIM / 4);
    cast_wt_kernel<<<(3 * DIM * DIM) / 256, 256, 0, stream>>>(W1, W2, W3, Wt);
    bounds_kernel<<<(M_NNZ + 255) / 256, 256, 0, stream>>>(adj_row, M_NNZ, rs, re);
    bounds_kernel<<<(P_PAIRS + 255) / 256, 256, 0, stream>>>(cn_edge, P_PAIRS, es, ee);

    agg_kernel<<<N_NODES, 128, 0, stream>>>(x, xh, rs, re, adj_col, hA);

    const int gemm_grid = (N_NODES + 63) / 64;
    gemm_f16<true ><<<gemm_grid, 256, 0, stream>>>(hA, Wt,               b1, hB);
    gemm_f16<true ><<<gemm_grid, 256, 0, stream>>>(hB, Wt + 16384,       b2, hA);
    gemm_f16<false><<<gemm_grid, 256, 0, stream>>>(hA, Wt + 32768,       b3, hB);

    norm_kernel<<<N_NODES / 4, 256, 0, stream>>>(hB, norms);
    edge_kernel<<<E_EDGES / 4, 256, 0, stream>>>(hB, norms, edges, es, ee, cn_node, out);
}

// Round 3
// 396.586 us; speedup vs baseline: 2.0010x; 1.2761x over previous
//
#include <hip/hip_runtime.h>
#include <math.h>

constexpr int N_NODES = 100000;
constexpr int DIM     = 128;
constexpr int M_NNZ   = 3200000;
constexpr int E_EDGES = 200000;
constexpr int P_PAIRS = 500000;

typedef _Float16 half8  __attribute__((ext_vector_type(8)));
typedef _Float16 half4t __attribute__((ext_vector_type(4)));
typedef _Float16 half2t __attribute__((ext_vector_type(2)));
typedef float    f32x4  __attribute__((ext_vector_type(4)));

// xh = (fp16)x, 4 elems/thread
__global__ void cast_x_kernel(const float* __restrict__ x, _Float16* __restrict__ xh, int n4) {
    int i = blockIdx.x * blockDim.x + threadIdx.x;
    if (i < n4) {
        float4 v = ((const float4*)x)[i];
        half4t o = { (_Float16)v.x, (_Float16)v.y, (_Float16)v.z, (_Float16)v.w };
        ((half4t*)xh)[i] = o;
    }
}

// Wt[m][n][k] = (fp16) W_m[k][n]  (transposed so MFMA B-fragments are contiguous 16B)
__global__ void cast_wt_kernel(const float* __restrict__ W1, const float* __restrict__ W2,
                               const float* __restrict__ W3, _Float16* __restrict__ Wt) {
    int tid = blockIdx.x * blockDim.x + threadIdx.x;  // 3*128*128
    int m = tid >> 14, n = (tid >> 7) & 127, k = tid & 127;
    const float* W = (m == 0) ? W1 : (m == 1) ? W2 : W3;
    Wt[tid] = (_Float16)W[k * DIM + n];
}

// Segment bounds of sorted arr, self-initializing: absent segments get start==end.
__global__ void bounds_kernel(const int* __restrict__ arr, int len,
                              int* __restrict__ rs, int* __restrict__ re, int nseg) {
    int p = blockIdx.x * blockDim.x + threadIdx.x;
    if (p >= len) return;
    int v = arr[p];
    if (p == 0) {
        rs[v] = 0;
        for (int w = 0; w < v; ++w) { rs[w] = 0; re[w] = 0; }
    } else {
        int pv = arr[p - 1];
        if (pv != v) {
            re[pv] = p; rs[v] = p;
            for (int w = pv + 1; w < v; ++w) { rs[w] = p; re[w] = p; }
        }
    }
    if (p == len - 1) {
        re[v] = len;
        for (int w = v + 1; w < nseg; ++w) { rs[w] = len; re[w] = len; }
    }
}

// h0[i] = fp16( xh[i] + (sum_j xh[j]) / (deg+1e-6) ). One WAVE per node.
// Lane layout: group g=lane>>4 handles neighbor 4k+g; lanes within group cover
// the 128-elem row as 16 x half8 (16B/lane). fp16 packed accumulate, fp32 reduce.
__global__ __launch_bounds__(256) void agg_kernel(
    const _Float16* __restrict__ xh,
    const int* __restrict__ rs, const int* __restrict__ re,
    const int* __restrict__ adj_col, _Float16* __restrict__ h0) {
    const int wave = threadIdx.x >> 6, lane = threadIdx.x & 63;
    const int node = blockIdx.x * 4 + wave;
    const int start = rs[node], end = re[node];
    const int g = lane >> 4;
    const int e8 = (lane & 15) * 8;

    half8 acc = {};
    for (int base = start; base < end; base += 64) {
        const int chunk = min(64, end - base);
        const int colreg = adj_col[base + min(lane, chunk - 1)];
        for (int j = 0; j < chunk; j += 4) {
            const int idx = j + g;
            const int c = __shfl(colreg, min(idx, chunk - 1));
            const half8 hv = *(const half8*)(xh + (size_t)c * DIM + e8);
            if (idx < chunk) acc += hv;
        }
    }
    float fa[8];
    #pragma unroll
    for (int t = 0; t < 8; ++t) {
        float f = (float)acc[t];
        f += __shfl_xor(f, 16);
        f += __shfl_xor(f, 32);
        fa[t] = f;
    }
    if (g == 0) {
        const float inv = 1.f / ((float)(end - start) + 1e-6f);
        const half8 xr = *(const half8*)(xh + (size_t)node * DIM + e8);
        half8 o;
        #pragma unroll
        for (int t = 0; t < 8; ++t) o[t] = (_Float16)((float)xr[t] + fa[t] * inv);
        *(half8*)(h0 + (size_t)node * DIM + e8) = o;
    }
}

// C = (relu?)(A @ W + b). Operand-swapped MFMA: mfma(wF, aF) yields the
// TRANSPOSED tile, so lane (q,l16) holds C[row=rBase+l16][col=c*16+q*4+reg],
// reg=0..3 -> 4 consecutive cols, packed half4 8-B stores. 32 rows/wave
// (two A fragments share each W fragment). NORM: fuse rnorm=1/||row|| epilogue.
template <bool RELU, bool NORM>
__global__ __launch_bounds__(256) void gemm_f16(
    const _Float16* __restrict__ A, const _Float16* __restrict__ Wt,
    const float* __restrict__ bias, _Float16* __restrict__ C,
    float* __restrict__ rnorm) {
    const int lane = threadIdx.x & 63;
    const int wave = threadIdx.x >> 6;
    const int q = lane >> 4, l16 = lane & 15;
    const int rBase = blockIdx.x * 128 + wave * 32;

    const int row0 = rBase + l16, row1 = rBase + 16 + l16;
    const int r0 = min(row0, N_NODES - 1), r1 = min(row1, N_NODES - 1);
    const _Float16* Ap0 = A + (size_t)r0 * DIM + q * 8;
    const _Float16* Ap1 = A + (size_t)r1 * DIM + q * 8;
    half8 a0[4], a1[4];
    #pragma unroll
    for (int t = 0; t < 4; ++t) {
        a0[t] = *(const half8*)(Ap0 + t * 32);
        a1[t] = *(const half8*)(Ap1 + t * 32);
    }

    float s0 = 0.f, s1 = 0.f;
    #pragma unroll
    for (int c = 0; c < 8; ++c) {
        f32x4 acc0 = {0.f, 0.f, 0.f, 0.f}, acc1 = {0.f, 0.f, 0.f, 0.f};
        const _Float16* Wp = Wt + (size_t)(c * 16 + l16) * DIM + q * 8;
        #pragma unroll
        for (int t = 0; t < 4; ++t) {
            const half8 w = *(const half8*)(Wp + t * 32);
            acc0 = __builtin_amdgcn_mfma_f32_16x16x32_f16(w, a0[t], acc0, 0, 0, 0);
            acc1 = __builtin_amdgcn_mfma_f32_16x16x32_f16(w, a1[t], acc1, 0, 0, 0);
        }
        const int colBase = c * 16 + q * 4;
        const float4 bb = *(const float4*)(bias + colBase);
        float v0[4], v1[4];
        #pragma unroll
        for (int i = 0; i < 4; ++i) {
            v0[i] = acc0[i] + ((const float*)&bb)[i];
            v1[i] = acc1[i] + ((const float*)&bb)[i];
            if (RELU) { v0[i] = fmaxf(v0[i], 0.f); v1[i] = fmaxf(v1[i], 0.f); }
        }
        if (NORM) {
            s0 += v0[0]*v0[0] + v0[1]*v0[1] + v0[2]*v0[2] + v0[3]*v0[3];
            s1 += v1[0]*v1[0] + v1[1]*v1[1] + v1[2]*v1[2] + v1[3]*v1[3];
        }
        half4t o0 = { (_Float16)v0[0], (_Float16)v0[1], (_Float16)v0[2], (_Float16)v0[3] };
        half4t o1 = { (_Float16)v1[0], (_Float16)v1[1], (_Float16)v1[2], (_Float16)v1[3] };
        if (row0 < N_NODES) *(half4t*)(C + (size_t)row0 * DIM + colBase) = o0;
        if (row1 < N_NODES) *(half4t*)(C + (size_t)row1 * DIM + colBase) = o1;
    }
    if (NORM) {
        s0 += __shfl_xor(s0, 16); s0 += __shfl_xor(s0, 32);
        s1 += __shfl_xor(s1, 16); s1 += __shfl_xor(s1, 32);
        if (q == 0) {
            if (row0 < N_NODES) rnorm[row0] = 1.f / fmaxf(sqrtf(s0), 1e-4f);
            if (row1 < N_NODES) rnorm[row1] = 1.f / fmaxf(sqrtf(s1), 1e-4f);
        }
    }
}

// One wave per query edge, 4 common-neighbor pairs in flight (16-lane groups,
// half8/lane = one 256B row per group), v_dot2_f32_f16 dots, fused sigmoid.
__global__ __launch_bounds__(256) void edge_kernel(
    const _Float16* __restrict__ h, const float* __restrict__ rnorm,
    const int* __restrict__ edges, const int* __restrict__ es,
    const int* __restrict__ ee, const int* __restrict__ cn_node,
    float* __restrict__ out) {
    const int wave = threadIdx.x >> 6, lane = threadIdx.x & 63;
    const int e = blockIdx.x * 4 + wave;
    const int g = lane >> 4;
    const int e8 = (lane & 15) * 8;

    const int start = es[e], end = ee[e];
    float sum = 0.f;
    if (end > start) {
        const int u = edges[e], v = edges[E_EDGES + e];
        const half8 hu = *(const half8*)(h + (size_t)u * DIM + e8);
        const half8 hv = *(const half8*)(h + (size_t)v * DIM + e8);
        half2t hu2[4], hv2[4];
        #pragma unroll
        for (int t = 0; t < 4; ++t) {
            hu2[t] = half2t{hu[2 * t], hu[2 * t + 1]};
            hv2[t] = half2t{hv[2 * t], hv[2 * t + 1]};
        }
        const float rnuv = rnorm[u] * rnorm[v];
        for (int p = start; p < end; p += 4) {
            const int idx = p + g;
            const int c = cn_node[min(idx, end - 1)];
            const half8 hc = *(const half8*)(h + (size_t)c * DIM + e8);
            float duc = 0.f, dvc = 0.f;
            #pragma unroll
            for (int t = 0; t < 4; ++t) {
                half2t c2 = half2t{hc[2 * t], hc[2 * t + 1]};
                duc = __builtin_amdgcn_fdot2(hu2[t], c2, duc, false);
                dvc = __builtin_amdgcn_fdot2(hv2[t], c2, dvc, false);
            }
            #pragma unroll
            for (int off = 1; off < 16; off <<= 1) {
                duc += __shfl_xor(duc, off);
                dvc += __shfl_xor(dvc, off);
            }
            if (idx < end) {
                const float rc = rnorm[c];
                sum += duc * dvc * rnuv * rc * rc;
            }
        }
        sum += __shfl_xor(sum, 16);
        sum += __shfl_xor(sum, 32);
    }
    if (lane == 0) out[e] = 1.f / (1.f + expf(-sum));
}

extern "C" void kernel_launch(void* const* d_in, const int* in_sizes, int n_in,
                              void* d_out, int out_size, void* d_ws, size_t ws_size,
                              hipStream_t stream) {
    const float* x     = (const float*)d_in[0];
    const int* adj_row = (const int*)d_in[1];
    const int* adj_col = (const int*)d_in[2];
    const int* edges   = (const int*)d_in[3];
    const int* cn_edge = (const int*)d_in[4];
    const int* cn_node = (const int*)d_in[5];
    // d_in[6] = cn_valid: all true; ignored.
    const float* W1 = (const float*)d_in[7];
    const float* b1 = (const float*)d_in[8];
    const float* W2 = (const float*)d_in[9];
    const float* b2 = (const float*)d_in[10];
    const float* W3 = (const float*)d_in[11];
    const float* b3 = (const float*)d_in[12];
    float* out = (float*)d_out;

    char* base = (char*)d_ws;
    _Float16* xh    = (_Float16*)base;               // 25.6 MB
    _Float16* hA    = (_Float16*)(base + 25600000);  // 25.6 MB
    _Float16* hB    = (_Float16*)(base + 51200000);  // 25.6 MB
    _Float16* Wt    = (_Float16*)(base + 76800000);  // 98304 B
    float*    rnorm = (float*)(base + 76996608);     // 400000 B
    int*      rs    = (int*)(base + 77396608);
    int*      re    = (int*)(base + 77796608);
    int*      es    = (int*)(base + 78196608);
    int*      ee    = (int*)(base + 78996608);       // end ~79.8 MB

    cast_x_kernel<<<(N_NODES * DIM / 4 + 255) / 256, 256, 0, stream>>>(x, xh, N_NODES * DIM / 4);
    cast_wt_kernel<<<(3 * DIM * DIM) / 256, 256, 0, stream>>>(W1, W2, W3, Wt);
    bounds_kernel<<<(M_NNZ + 255) / 256, 256, 0, stream>>>(adj_row, M_NNZ, rs, re, N_NODES);
    bounds_kernel<<<(P_PAIRS + 255) / 256, 256, 0, stream>>>(cn_edge, P_PAIRS, es, ee, E_EDGES);

    agg_kernel<<<N_NODES / 4, 256, 0, stream>>>(xh, rs, re, adj_col, hA);

    const int gemm_grid = (N_NODES + 127) / 128;
    gemm_f16<true , false><<<gemm_grid, 256, 0, stream>>>(hA, Wt,         b1, hB, nullptr);
    gemm_f16<true , false><<<gemm_grid, 256, 0, stream>>>(hB, Wt + 16384, b2, hA, nullptr);
    gemm_f16<false, true ><<<gemm_grid, 256, 0, stream>>>(hA, Wt + 32768, b3, hB, rnorm);

    edge_kernel<<<E_EDGES / 4, 256, 0, stream>>>(hB, rnorm, edges, es, ee, cn_node, out);
}

// Round 4
// 378.598 us; speedup vs baseline: 2.0961x; 1.0475x over previous
//
#include <hip/hip_runtime.h>
#include <math.h>

constexpr int N_NODES = 100000;
constexpr int DIM     = 128;
constexpr int M_NNZ   = 3200000;
constexpr int E_EDGES = 200000;
constexpr int P_PAIRS = 500000;

typedef _Float16 half8  __attribute__((ext_vector_type(8)));
typedef _Float16 half4t __attribute__((ext_vector_type(4)));
typedef _Float16 half2t __attribute__((ext_vector_type(2)));
typedef float    f32x4  __attribute__((ext_vector_type(4)));

// xh = (fp16)x, 4 elems/thread
__global__ void cast_x_kernel(const float* __restrict__ x, _Float16* __restrict__ xh, int n4) {
    int i = blockIdx.x * blockDim.x + threadIdx.x;
    if (i < n4) {
        float4 v = ((const float4*)x)[i];
        half4t o = { (_Float16)v.x, (_Float16)v.y, (_Float16)v.z, (_Float16)v.w };
        ((half4t*)xh)[i] = o;
    }
}

// Wt[m][n][k] = (fp16) W_m[k][n]  (transposed so MFMA B-fragments are contiguous 16B)
__global__ void cast_wt_kernel(const float* __restrict__ W1, const float* __restrict__ W2,
                               const float* __restrict__ W3, _Float16* __restrict__ Wt) {
    int tid = blockIdx.x * blockDim.x + threadIdx.x;  // 3*128*128
    int m = tid >> 14, n = (tid >> 7) & 127, k = tid & 127;
    const float* W = (m == 0) ? W1 : (m == 1) ? W2 : W3;
    Wt[tid] = (_Float16)W[k * DIM + n];
}

// Segment bounds of sorted arr, self-initializing: absent segments get start==end.
__global__ void bounds_kernel(const int* __restrict__ arr, int len,
                              int* __restrict__ rs, int* __restrict__ re, int nseg) {
    int p = blockIdx.x * blockDim.x + threadIdx.x;
    if (p >= len) return;
    int v = arr[p];
    if (p == 0) {
        rs[v] = 0;
        for (int w = 0; w < v; ++w) { rs[w] = 0; re[w] = 0; }
    } else {
        int pv = arr[p - 1];
        if (pv != v) {
            re[pv] = p; rs[v] = p;
            for (int w = pv + 1; w < v; ++w) { rs[w] = p; re[w] = p; }
        }
    }
    if (p == len - 1) {
        re[v] = len;
        for (int w = v + 1; w < nseg; ++w) { rs[w] = len; re[w] = len; }
    }
}

// h0[i] = fp16( xh[i] + (sum_j xh[j]) / (deg+1e-6) ). One WAVE per node.
// Group g=lane>>4 covers one neighbor row per load (16 lanes x half8 = 256B row).
// Bulk loop: 16 neighbors/iter = 4 independent unconditional loads into 4
// accumulators (memory-level parallelism); masked tail for deg%16.
__global__ __launch_bounds__(256) void agg_kernel(
    const _Float16* __restrict__ xh,
    const int* __restrict__ rs, const int* __restrict__ re,
    const int* __restrict__ adj_col, _Float16* __restrict__ h0) {
    const int wave = threadIdx.x >> 6, lane = threadIdx.x & 63;
    const int node = blockIdx.x * 4 + wave;
    const int start = rs[node], cnt = re[node] - start;
    const int g = lane >> 4;
    const int e8 = (lane & 15) * 8;

    half8 acc0 = {}, acc1 = {}, acc2 = {}, acc3 = {};
    for (int base = 0; base < cnt; base += 64) {
        const int chunk = min(64, cnt - base);
        const int colreg = adj_col[start + base + min(lane, chunk - 1)];
        int j = 0;
        for (; j + 16 <= chunk; j += 16) {
            const int c0 = __shfl(colreg, j + g);
            const int c1 = __shfl(colreg, j + 4 + g);
            const int c2 = __shfl(colreg, j + 8 + g);
            const int c3 = __shfl(colreg, j + 12 + g);
            const half8 v0 = *(const half8*)(xh + (size_t)c0 * DIM + e8);
            const half8 v1 = *(const half8*)(xh + (size_t)c1 * DIM + e8);
            const half8 v2 = *(const half8*)(xh + (size_t)c2 * DIM + e8);
            const half8 v3 = *(const half8*)(xh + (size_t)c3 * DIM + e8);
            acc0 += v0; acc1 += v1; acc2 += v2; acc3 += v3;
        }
        for (; j < chunk; j += 4) {
            const int idx = j + g;
            const int c = __shfl(colreg, min(idx, chunk - 1));
            const half8 v = *(const half8*)(xh + (size_t)c * DIM + e8);
            if (idx < chunk) acc0 += v;
        }
    }
    acc0 += acc1; acc2 += acc3; acc0 += acc2;

    float fa[8];
    #pragma unroll
    for (int t = 0; t < 8; ++t) {
        float f = (float)acc0[t];
        f += __shfl_xor(f, 16);
        f += __shfl_xor(f, 32);
        fa[t] = f;
    }
    if (g == 0) {
        const float inv = 1.f / ((float)cnt + 1e-6f);
        const half8 xr = *(const half8*)(xh + (size_t)node * DIM + e8);
        half8 o;
        #pragma unroll
        for (int t = 0; t < 8; ++t) o[t] = (_Float16)((float)xr[t] + fa[t] * inv);
        *(half8*)(h0 + (size_t)node * DIM + e8) = o;
    }
}

// Fused 3-layer MLP: H = (relu(relu(A@W1+b1)@W2+b2))@W3+b3, plus rnorm=1/||row||.
// One wave owns 32 rows for all 128 cols; between layers the C-layout
// (row=l16/16+l16, cols q*4+reg per coltile) is re-shaped to the A-fragment
// layout (row=l16, k=q*8+t*32) via a per-wave padded LDS tile (2-way banks).
// Operand-swapped MFMA as in R3: mfma(wFrag, aFrag) -> transposed C tile.
__global__ __launch_bounds__(256) void mlp_kernel(
    const _Float16* __restrict__ A, const _Float16* __restrict__ Wt,
    const float* __restrict__ b1, const float* __restrict__ b2,
    const float* __restrict__ b3, _Float16* __restrict__ H,
    float* __restrict__ rnorm) {
    __shared__ __align__(16) _Float16 lds[4][32][136];  // 34.8 KB; +8 pad
    const int lane = threadIdx.x & 63;
    const int wave = threadIdx.x >> 6;
    const int q = lane >> 4, l16 = lane & 15;
    const int rBase = blockIdx.x * 128 + wave * 32;
    _Float16 (*__restrict__ L)[136] = lds[wave];

    const int row0 = rBase + l16, row1 = rBase + 16 + l16;
    const int r0 = min(row0, N_NODES - 1), r1 = min(row1, N_NODES - 1);
    const _Float16* Ap0 = A + (size_t)r0 * DIM + q * 8;
    const _Float16* Ap1 = A + (size_t)r1 * DIM + q * 8;
    half8 a0[4], a1[4];
    #pragma unroll
    for (int t = 0; t < 4; ++t) {
        a0[t] = *(const half8*)(Ap0 + t * 32);
        a1[t] = *(const half8*)(Ap1 + t * 32);
    }

    #pragma unroll
    for (int layer = 0; layer < 3; ++layer) {
        const _Float16* W = Wt + layer * 16384;
        const float* bias = (layer == 0) ? b1 : (layer == 1) ? b2 : b3;
        float s0 = 0.f, s1 = 0.f;
        #pragma unroll
        for (int c = 0; c < 8; ++c) {
            f32x4 acc0 = {0.f, 0.f, 0.f, 0.f}, acc1 = {0.f, 0.f, 0.f, 0.f};
            const _Float16* Wp = W + (size_t)(c * 16 + l16) * DIM + q * 8;
            #pragma unroll
            for (int t = 0; t < 4; ++t) {
                const half8 w = *(const half8*)(Wp + t * 32);
                acc0 = __builtin_amdgcn_mfma_f32_16x16x32_f16(w, a0[t], acc0, 0, 0, 0);
                acc1 = __builtin_amdgcn_mfma_f32_16x16x32_f16(w, a1[t], acc1, 0, 0, 0);
            }
            const int colBase = c * 16 + q * 4;
            const float4 bb = *(const float4*)(bias + colBase);
            half4t o0, o1;
            #pragma unroll
            for (int i = 0; i < 4; ++i) {
                float v0 = acc0[i] + ((const float*)&bb)[i];
                float v1 = acc1[i] + ((const float*)&bb)[i];
                if (layer < 2) { v0 = fmaxf(v0, 0.f); v1 = fmaxf(v1, 0.f); }
                else { s0 += v0 * v0; s1 += v1 * v1; }
                o0[i] = (_Float16)v0; o1[i] = (_Float16)v1;
            }
            if (layer < 2) {
                *(half4t*)&L[l16][colBase]      = o0;
                *(half4t*)&L[16 + l16][colBase] = o1;
            } else {
                if (row0 < N_NODES) *(half4t*)(H + (size_t)row0 * DIM + colBase) = o0;
                if (row1 < N_NODES) *(half4t*)(H + (size_t)row1 * DIM + colBase) = o1;
            }
        }
        if (layer < 2) {
            __syncthreads();
            #pragma unroll
            for (int t = 0; t < 4; ++t) {
                a0[t] = *(const half8*)&L[l16][q * 8 + t * 32];
                a1[t] = *(const half8*)&L[16 + l16][q * 8 + t * 32];
            }
        } else {
            s0 += __shfl_xor(s0, 16); s0 += __shfl_xor(s0, 32);
            s1 += __shfl_xor(s1, 16); s1 += __shfl_xor(s1, 32);
            if (q == 0) {
                if (row0 < N_NODES) rnorm[row0] = 1.f / fmaxf(sqrtf(s0), 1e-4f);
                if (row1 < N_NODES) rnorm[row1] = 1.f / fmaxf(sqrtf(s1), 1e-4f);
            }
        }
    }
}

// One wave per query edge; 8 common-neighbor rows in flight per iteration
// (2 per 16-lane group), v_dot2_f32_f16 dots, fused sigmoid.
__global__ __launch_bounds__(256) void edge_kernel(
    const _Float16* __restrict__ h, const float* __restrict__ rnorm,
    const int* __restrict__ edges, const int* __restrict__ es,
    const int* __restrict__ ee, const int* __restrict__ cn_node,
    float* __restrict__ out) {
    const int wave = threadIdx.x >> 6, lane = threadIdx.x & 63;
    const int e = blockIdx.x * 4 + wave;
    const int g = lane >> 4;
    const int e8 = (lane & 15) * 8;

    const int start = es[e], end = ee[e];
    float sum = 0.f;
    if (end > start) {
        const int u = edges[e], v = edges[E_EDGES + e];
        const half8 hu = *(const half8*)(h + (size_t)u * DIM + e8);
        const half8 hv = *(const half8*)(h + (size_t)v * DIM + e8);
        half2t hu2[4], hv2[4];
        #pragma unroll
        for (int t = 0; t < 4; ++t) {
            hu2[t] = half2t{hu[2 * t], hu[2 * t + 1]};
            hv2[t] = half2t{hv[2 * t], hv[2 * t + 1]};
        }
        const float rnuv = rnorm[u] * rnorm[v];
        for (int p = start; p < end; p += 8) {
            const int i0 = p + g, i1 = p + 4 + g;
            const int c0 = cn_node[min(i0, end - 1)];
            const int c1 = cn_node[min(i1, end - 1)];
            const half8 hc0 = *(const half8*)(h + (size_t)c0 * DIM + e8);
            const half8 hc1 = *(const half8*)(h + (size_t)c1 * DIM + e8);
            float duc0 = 0.f, dvc0 = 0.f, duc1 = 0.f, dvc1 = 0.f;
            #pragma unroll
            for (int t = 0; t < 4; ++t) {
                half2t a = half2t{hc0[2 * t], hc0[2 * t + 1]};
                half2t b = half2t{hc1[2 * t], hc1[2 * t + 1]};
                duc0 = __builtin_amdgcn_fdot2(hu2[t], a, duc0, false);
                dvc0 = __builtin_amdgcn_fdot2(hv2[t], a, dvc0, false);
                duc1 = __builtin_amdgcn_fdot2(hu2[t], b, duc1, false);
                dvc1 = __builtin_amdgcn_fdot2(hv2[t], b, dvc1, false);
            }
            #pragma unroll
            for (int off = 1; off < 16; off <<= 1) {
                duc0 += __shfl_xor(duc0, off);
                dvc0 += __shfl_xor(dvc0, off);
                duc1 += __shfl_xor(duc1, off);
                dvc1 += __shfl_xor(dvc1, off);
            }
            if (i0 < end) {
                const float rc = rnorm[c0];
                sum += duc0 * dvc0 * rnuv * rc * rc;
            }
            if (i1 < end) {
                const float rc = rnorm[c1];
                sum += duc1 * dvc1 * rnuv * rc * rc;
            }
        }
        sum += __shfl_xor(sum, 16);
        sum += __shfl_xor(sum, 32);
    }
    if (lane == 0) out[e] = 1.f / (1.f + expf(-sum));
}

extern "C" void kernel_launch(void* const* d_in, const int* in_sizes, int n_in,
                              void* d_out, int out_size, void* d_ws, size_t ws_size,
                              hipStream_t stream) {
    const float* x     = (const float*)d_in[0];
    const int* adj_row = (const int*)d_in[1];
    const int* adj_col = (const int*)d_in[2];
    const int* edges   = (const int*)d_in[3];
    const int* cn_edge = (const int*)d_in[4];
    const int* cn_node = (const int*)d_in[5];
    // d_in[6] = cn_valid: all true; ignored.
    const float* W1 = (const float*)d_in[7];
    const float* b1 = (const float*)d_in[8];
    const float* W2 = (const float*)d_in[9];
    const float* b2 = (const float*)d_in[10];
    const float* W3 = (const float*)d_in[11];
    const float* b3 = (const float*)d_in[12];
    float* out = (float*)d_out;

    char* base = (char*)d_ws;
    _Float16* xh    = (_Float16*)base;               // 25.6 MB
    _Float16* hA    = (_Float16*)(base + 25600000);  // 25.6 MB
    _Float16* hB    = (_Float16*)(base + 51200000);  // 25.6 MB
    _Float16* Wt    = (_Float16*)(base + 76800000);  // 98304 B
    float*    rnorm = (float*)(base + 76996608);     // 400000 B
    int*      rs    = (int*)(base + 77396608);
    int*      re    = (int*)(base + 77796608);
    int*      es    = (int*)(base + 78196608);
    int*      ee    = (int*)(base + 78996608);       // end ~79.8 MB

    cast_x_kernel<<<(N_NODES * DIM / 4 + 255) / 256, 256, 0, stream>>>(x, xh, N_NODES * DIM / 4);
    cast_wt_kernel<<<(3 * DIM * DIM) / 256, 256, 0, stream>>>(W1, W2, W3, Wt);
    bounds_kernel<<<(M_NNZ + 255) / 256, 256, 0, stream>>>(adj_row, M_NNZ, rs, re, N_NODES);
    bounds_kernel<<<(P_PAIRS + 255) / 256, 256, 0, stream>>>(cn_edge, P_PAIRS, es, ee, E_EDGES);

    agg_kernel<<<N_NODES / 4, 256, 0, stream>>>(xh, rs, re, adj_col, hA);

    mlp_kernel<<<(N_NODES + 127) / 128, 256, 0, stream>>>(hA, Wt, b1, b2, b3, hB, rnorm);

    edge_kernel<<<E_EDGES / 4, 256, 0, stream>>>(hB, rnorm, edges, es, ee, cn_node, out);
}